// Round 1
// 1746.788 us; speedup vs baseline: 2.2623x; 2.2623x over previous
//
#include <hip/hip_runtime.h>

#define NN 100000
#define NE 1600000
#define DIM 128
#define LDH 132   // padded LDS leading dim (breaks power-of-2 bank strides)

// ---------------------------------------------------------------------------
// ws layout (bytes):
//   [0, 256)                 int flag (flag[0] = OR of odd index words)
//   [256, 400256)            cnt[NN]    edge-count histogram (must be zeroed)
//   [400256, 800256)         start[NN]  exclusive prefix (CSR row offsets)
//   [800256, 1200256)        cursor[NN] fill cursors; after fill == row ends
//   [1200256, 7600256)       elist[NE]  edge ids sorted by destination
//   [7600384, 58800384)      msg[NN*DIM] aggregated messages (written fully)
// ---------------------------------------------------------------------------
#define OFF_CNT    256
#define OFF_START  400256
#define OFF_CURSOR 800256
#define OFF_ELIST  1200256
#define OFF_MSG    7600384   // 16B aligned

// Detect whether edge_index is stored as int64 (odd 32-bit words of the first
// row are all zero) or int32. Writes OR of odd words into orflag[0].
__global__ void detect_kernel(const int* __restrict__ idx32, int* __restrict__ orflag) {
    int acc = 0;
    int i = blockIdx.x * blockDim.x + threadIdx.x;
    const int stride = gridDim.x * blockDim.x;
    for (; i < NE; i += stride) acc |= idx32[2 * i + 1];
#pragma unroll
    for (int m = 32; m >= 1; m >>= 1) acc |= __shfl_xor(acc, m);
    if ((threadIdx.x & 63) == 0 && acc != 0) atomicOr(orflag, 1);
}

__device__ __forceinline__ int load_dst(const int* __restrict__ idx32, int is64, int i) {
    return is64 ? idx32[2 * (NE + i)]   // low word of int64
                : idx32[NE + i];
}

// Pass 1: per-destination edge counts. 1.6M int atomics on an L2-resident table.
__global__ void hist_kernel(const int* __restrict__ idx32,
                            const int* __restrict__ orflag,
                            int* __restrict__ cnt) {
    const int is64 = (orflag[0] == 0);
    int i = blockIdx.x * blockDim.x + threadIdx.x;
    const int stride = gridDim.x * blockDim.x;
    for (; i < NE; i += stride)
        atomicAdd(&cnt[load_dst(idx32, is64, i)], 1);
}

// Pass 2: exclusive scan of cnt -> start (and cursor copy). Single block,
// 1024 threads, 98 chunks; trivially fast vs. everything else.
__global__ void __launch_bounds__(1024)
scan_kernel(const int* __restrict__ cnt, int* __restrict__ start,
            int* __restrict__ cursor) {
    __shared__ int wsum[16];
    __shared__ int carry_s;
    const int t = threadIdx.x;
    const int lane = t & 63, wid = t >> 6;
    if (t == 0) carry_s = 0;
    __syncthreads();
    for (int base = 0; base < NN; base += 1024) {
        const int i = base + t;
        const int v = (i < NN) ? cnt[i] : 0;
        int s = v;  // inclusive scan within wave
#pragma unroll
        for (int d = 1; d < 64; d <<= 1) {
            int u = __shfl_up(s, d);
            if (lane >= d) s += u;
        }
        if (lane == 63) wsum[wid] = s;
        __syncthreads();
        if (t == 0) {  // serial scan of the 16 wave sums + carry
            int acc = carry_s;
#pragma unroll
            for (int w = 0; w < 16; ++w) { int x = wsum[w]; wsum[w] = acc; acc += x; }
            carry_s = acc;
        }
        __syncthreads();
        const int ex = wsum[wid] + s - v;  // exclusive prefix
        if (i < NN) { start[i] = ex; cursor[i] = ex; }
        __syncthreads();  // wsum/carry reuse next chunk
    }
}

// Pass 3: counting-sort fill. elist[] gets edge ids grouped by destination.
__global__ void fill_kernel(const int* __restrict__ idx32,
                            const int* __restrict__ orflag,
                            int* __restrict__ cursor, int* __restrict__ elist) {
    const int is64 = (orflag[0] == 0);
    int i = blockIdx.x * blockDim.x + threadIdx.x;
    const int stride = gridDim.x * blockDim.x;
    for (; i < NE; i += stride) {
        const int dst = load_dst(idx32, is64, i);
        const int pos = atomicAdd(&cursor[dst], 1);
        elist[pos] = i;
    }
}

// Pass 4: gather-sum. 32 threads (float4 each) per node, 8 nodes per block.
// Each edge row is one 512B contiguous burst; msg written exactly once.
__global__ void __launch_bounds__(256)
gather_kernel(const float4* __restrict__ e4, const int* __restrict__ start,
              const int* __restrict__ cursor, const int* __restrict__ elist,
              float4* __restrict__ msg4) {
    const int t = threadIdx.x;
    const int node = blockIdx.x * 8 + (t >> 5);
    const int c4 = t & 31;
    const int beg = start[node];
    const int end = cursor[node];  // == beg + degree after fill
    float4 a0 = {0.f, 0.f, 0.f, 0.f}, a1 = a0, a2 = a0, a3 = a0;
    int i = beg;
    for (; i + 4 <= end; i += 4) {  // 4 rows in flight
        const int e0 = elist[i], e1 = elist[i + 1], e2 = elist[i + 2], e3 = elist[i + 3];
        const float4 v0 = e4[(size_t)e0 * 32 + c4];
        const float4 v1 = e4[(size_t)e1 * 32 + c4];
        const float4 v2 = e4[(size_t)e2 * 32 + c4];
        const float4 v3 = e4[(size_t)e3 * 32 + c4];
        a0.x += v0.x; a0.y += v0.y; a0.z += v0.z; a0.w += v0.w;
        a1.x += v1.x; a1.y += v1.y; a1.z += v1.z; a1.w += v1.w;
        a2.x += v2.x; a2.y += v2.y; a2.z += v2.z; a2.w += v2.w;
        a3.x += v3.x; a3.y += v3.y; a3.z += v3.z; a3.w += v3.w;
    }
    for (; i < end; ++i) {
        const float4 v0 = e4[(size_t)elist[i] * 32 + c4];
        a0.x += v0.x; a0.y += v0.y; a0.z += v0.z; a0.w += v0.w;
    }
    float4 r;
    r.x = (a0.x + a1.x) + (a2.x + a3.x);
    r.y = (a0.y + a1.y) + (a2.y + a3.y);
    r.z = (a0.z + a1.z) + (a2.z + a3.z);
    r.w = (a0.w + a1.w) + (a2.w + a3.w);
    msg4[(size_t)node * 32 + c4] = r;
}

// acc[ii][jj] += sum_k in[n0+ii][k] * W[k][j0+jj]   (in = LDS tile, W = global)
__device__ __forceinline__ void gemm_acc(const float* __restrict__ in,
                                         const float* __restrict__ W,
                                         float acc[4][4], int n0, int j0) {
#pragma unroll 4
    for (int k = 0; k < DIM; k += 4) {
        float4 w0 = *(const float4*)(W + (size_t)(k + 0) * DIM + j0);
        float4 w1 = *(const float4*)(W + (size_t)(k + 1) * DIM + j0);
        float4 w2 = *(const float4*)(W + (size_t)(k + 2) * DIM + j0);
        float4 w3 = *(const float4*)(W + (size_t)(k + 3) * DIM + j0);
#pragma unroll
        for (int ii = 0; ii < 4; ++ii) {
            float4 h = *(const float4*)(in + (n0 + ii) * LDH + k);
            acc[ii][0] += h.x * w0.x + h.y * w1.x + h.z * w2.x + h.w * w3.x;
            acc[ii][1] += h.x * w0.y + h.y * w1.y + h.z * w2.y + h.w * w3.y;
            acc[ii][2] += h.x * w0.z + h.y * w1.z + h.z * w2.z + h.w * w3.z;
            acc[ii][3] += h.x * w0.w + h.y * w1.w + h.z * w2.w + h.w * w3.w;
        }
    }
}

// Fused: concat-GEMM(W0) -> relu -> 2x hidden -> output -> GroupNorm -> +x
// One block = 32 nodes. h tiles live in LDS the whole time.
__global__ void __launch_bounds__(256)
mlp_kernel(const float* __restrict__ x, const float* __restrict__ msg,
           const float* __restrict__ W0, const float* __restrict__ b0,
           const float* __restrict__ Wh, const float* __restrict__ bh,
           const float* __restrict__ Wo, const float* __restrict__ bo,
           const float* __restrict__ gnw, const float* __restrict__ gnb,
           float* __restrict__ out) {
    __shared__ __align__(16) float xs[32][LDH];
    __shared__ __align__(16) float hA[32][LDH];
    __shared__ __align__(16) float mB[32][LDH];  // msg tile, later reused as hB

    const int t = threadIdx.x;
    const int nodeBase = blockIdx.x * 32;

    // Stage x and msg tiles (32 nodes x 128 ch), coalesced float4.
#pragma unroll
    for (int i = 0; i < 4; ++i) {
        int flat = t + i * 256;          // 0..1023
        int r = flat >> 5;
        int c = (flat & 31) * 4;
        *(float4*)&xs[r][c] = *(const float4*)(x + (size_t)(nodeBase + r) * DIM + c);
        *(float4*)&mB[r][c] = *(const float4*)(msg + (size_t)(nodeBase + r) * DIM + c);
    }
    __syncthreads();

    const int n0 = (t & 7) * 4;
    const int j0 = (t >> 3) * 4;
    float acc[4][4];

    // ---- layer 0: relu([x|msg] @ W0 + b0) -> hA
    {
        float4 bv = *(const float4*)(b0 + j0);
#pragma unroll
        for (int ii = 0; ii < 4; ++ii) {
            acc[ii][0] = bv.x; acc[ii][1] = bv.y; acc[ii][2] = bv.z; acc[ii][3] = bv.w;
        }
        gemm_acc(&xs[0][0], W0, acc, n0, j0);
        gemm_acc(&mB[0][0], W0 + (size_t)DIM * DIM, acc, n0, j0);
        __syncthreads();  // mB fully consumed before overwrite as hB
#pragma unroll
        for (int ii = 0; ii < 4; ++ii)
#pragma unroll
            for (int jj = 0; jj < 4; ++jj)
                hA[n0 + ii][j0 + jj] = fmaxf(acc[ii][jj], 0.0f);
    }
    __syncthreads();

    // ---- layer 1: relu(hA @ Wh[0] + bh[0]) -> mB(=hB)
    {
        float4 bv = *(const float4*)(bh + j0);
#pragma unroll
        for (int ii = 0; ii < 4; ++ii) {
            acc[ii][0] = bv.x; acc[ii][1] = bv.y; acc[ii][2] = bv.z; acc[ii][3] = bv.w;
        }
        gemm_acc(&hA[0][0], Wh, acc, n0, j0);
        __syncthreads();
#pragma unroll
        for (int ii = 0; ii < 4; ++ii)
#pragma unroll
            for (int jj = 0; jj < 4; ++jj)
                mB[n0 + ii][j0 + jj] = fmaxf(acc[ii][jj], 0.0f);
    }
    __syncthreads();

    // ---- layer 2: relu(hB @ Wh[1] + bh[1]) -> hA
    {
        float4 bv = *(const float4*)(bh + DIM + j0);
#pragma unroll
        for (int ii = 0; ii < 4; ++ii) {
            acc[ii][0] = bv.x; acc[ii][1] = bv.y; acc[ii][2] = bv.z; acc[ii][3] = bv.w;
        }
        gemm_acc(&mB[0][0], Wh + (size_t)DIM * DIM, acc, n0, j0);
        __syncthreads();
#pragma unroll
        for (int ii = 0; ii < 4; ++ii)
#pragma unroll
            for (int jj = 0; jj < 4; ++jj)
                hA[n0 + ii][j0 + jj] = fmaxf(acc[ii][jj], 0.0f);
    }
    __syncthreads();

    // ---- layer 3 (output): hA @ Wo + bo -> mB(=h3), no relu
    {
        float4 bv = *(const float4*)(bo + j0);
#pragma unroll
        for (int ii = 0; ii < 4; ++ii) {
            acc[ii][0] = bv.x; acc[ii][1] = bv.y; acc[ii][2] = bv.z; acc[ii][3] = bv.w;
        }
        gemm_acc(&hA[0][0], Wo, acc, n0, j0);
        __syncthreads();
#pragma unroll
        for (int ii = 0; ii < 4; ++ii)
#pragma unroll
            for (int jj = 0; jj < 4; ++jj)
                mB[n0 + ii][j0 + jj] = acc[ii][jj];
    }
    __syncthreads();

    // ---- GroupNorm(1 group over 128 ch) + residual, write out.
    // 8 threads per node, 16 channels each; lanes of a node group are
    // consecutive & 8-aligned -> shfl_xor reduction stays in-group.
    {
        const int n = t >> 3;
        const int c0 = (t & 7) * 16;
        float s = 0.0f, s2 = 0.0f;
#pragma unroll
        for (int c = 0; c < 16; ++c) {
            float v = mB[n][c0 + c];
            s += v; s2 += v * v;
        }
#pragma unroll
        for (int m = 1; m < 8; m <<= 1) {
            s  += __shfl_xor(s, m);
            s2 += __shfl_xor(s2, m);
        }
        const float mean = s * (1.0f / 128.0f);
        float var = s2 * (1.0f / 128.0f) - mean * mean;
        var = fmaxf(var, 0.0f);
        const float rs = rsqrtf(var + 1e-5f);
#pragma unroll
        for (int c = 0; c < 16; c += 4) {
            int cc = c0 + c;
            float4 gw = *(const float4*)(gnw + cc);
            float4 gb = *(const float4*)(gnb + cc);
            float4 hv = *(const float4*)&mB[n][cc];
            float4 xv = *(const float4*)&xs[n][cc];
            float4 o;
            o.x = xv.x + (hv.x - mean) * rs * gw.x + gb.x;
            o.y = xv.y + (hv.y - mean) * rs * gw.y + gb.y;
            o.z = xv.z + (hv.z - mean) * rs * gw.z + gb.z;
            o.w = xv.w + (hv.w - mean) * rs * gw.w + gb.w;
            *(float4*)(out + (size_t)(nodeBase + n) * DIM + cc) = o;
        }
    }
}

extern "C" void kernel_launch(void* const* d_in, const int* in_sizes, int n_in,
                              void* d_out, int out_size, void* d_ws, size_t ws_size,
                              hipStream_t stream) {
    const float* x   = (const float*)d_in[0];
    const float* e   = (const float*)d_in[1];
    const int*   idx = (const int*)d_in[2];
    const float* W0  = (const float*)d_in[3];
    const float* b0  = (const float*)d_in[4];
    const float* Wh  = (const float*)d_in[5];
    const float* bh  = (const float*)d_in[6];
    const float* Wo  = (const float*)d_in[7];
    const float* bo  = (const float*)d_in[8];
    const float* gnw = (const float*)d_in[9];
    const float* gnb = (const float*)d_in[10];
    float* out = (float*)d_out;

    char* ws = (char*)d_ws;
    int*   flag   = (int*)ws;
    int*   cnt    = (int*)(ws + OFF_CNT);
    int*   startp = (int*)(ws + OFF_START);
    int*   cursor = (int*)(ws + OFF_CURSOR);
    int*   elist  = (int*)(ws + OFF_ELIST);
    float* msg    = (float*)(ws + OFF_MSG);

    // Zero flag + histogram only (start/cursor/elist/msg are fully written).
    hipMemsetAsync(d_ws, 0, OFF_START, stream);

    detect_kernel<<<512, 256, 0, stream>>>(idx, flag);
    hist_kernel<<<2048, 256, 0, stream>>>(idx, flag, cnt);
    scan_kernel<<<1, 1024, 0, stream>>>(cnt, startp, cursor);
    fill_kernel<<<2048, 256, 0, stream>>>(idx, flag, cursor, elist);
    gather_kernel<<<NN / 8, 256, 0, stream>>>((const float4*)e, startp, cursor,
                                              elist, (float4*)msg);
    mlp_kernel<<<NN / 32, 256, 0, stream>>>(x, msg, W0, b0, Wh, bh, Wo, bo,
                                            gnw, gnb, out);
}